// Round 2
// baseline (846.960 us; speedup 1.0000x reference)
//
#include <hip/hip_runtime.h>
#include <hip/hip_cooperative_groups.h>

namespace cg = cooperative_groups;

#define N 6144
#define IN_SZ 1024
#define CHUNK 64
#define NCH_REC (N / CHUNK)        // 96
#define NCH_IN (IN_SZ / CHUNK)     // 16
#define NCH (NCH_REC + NCH_IN)     // 112
#define NBLK2 24                   // neuron-update blocks (N/256)
#define GRID 1024                  // co-resident: 4 blocks/CU x 256 CU
#define RPB (N / GRID)             // 6 W_rec rows per block in phase 3

typedef float v4f __attribute__((ext_vector_type(4)));
typedef float v2f __attribute__((ext_vector_type(2)));

// output layout (flat float32, return order)
#define OFF_SPK 0
#define OFF_ACT 6144
#define OFF_V 6154
#define OFF_MEM 12298
#define OFF_W 18442                // % 4 == 2 -> row stores are 8B-aligned
#define OFF_HIST 37767178

// Cross-XCD-safe handoff: per-XCD L2s are not coherent; plain stores read
// across grid.sync() came back stale in round 1. Agent-scope atomics go to
// the device coherence point.
#define AST(p, v) __hip_atomic_store((p), (v), __ATOMIC_RELAXED, __HIP_MEMORY_SCOPE_AGENT)
#define ALD(p) __hip_atomic_load((p), __ATOMIC_RELAXED, __HIP_MEMORY_SCOPE_AGENT)

__global__ __launch_bounds__(256, 4) void snn_fused(
    const float* __restrict__ Wrec, const float* __restrict__ Win,
    const float* __restrict__ hist, const float* __restrict__ inp,
    const float* __restrict__ V, const float* __restrict__ mem,
    const float* __restrict__ noise, const float* __restrict__ Wout,
    float* __restrict__ out, float* __restrict__ ws) {
  float* partial = ws;                      // 112*6144
  float* ws_post = ws + (size_t)NCH * N;    // 6144 (only cross-phase vector)
  const int tid = threadIdx.x;
  const int bid = blockIdx.x;
  cg::grid_group grid = cg::this_grid();
  __shared__ float sp[CHUNK];
  __shared__ float red[4][10];
  __shared__ unsigned char pre_b[N];   // 6 KB: pre spikes (from hist input)
  __shared__ unsigned char post_b[N];  // 6 KB: current spikes (handoff)

  // ---- phase 1: sparse spike-driven matvec partials (blocks 0..671) ----
  if (bid < 6 * NCH) {
    int bx = bid % 6;
    int by = bid / 6;
    bool isRec = by < NCH_REC;
    int rbase = (isRec ? by : by - NCH_REC) * CHUNK;
    const float* M = isRec ? Wrec : Win;
    if (tid < CHUNK)
      sp[tid] = isRec ? hist[2 * (rbase + tid) + 1] : inp[rbase + tid];
    __syncthreads();
    int j0 = (bx * 256 + tid) * 4;
    float4 acc = make_float4(0.f, 0.f, 0.f, 0.f);
    for (int r = 0; r < CHUNK; ++r) {
      if (sp[r] != 0.0f) {  // block-uniform: skip HBM read of silent rows
        const float4 w = *(const float4*)(M + (size_t)(rbase + r) * N + j0);
        acc.x += w.x; acc.y += w.y; acc.z += w.z; acc.w += w.w;
      }
    }
    float* pp = partial + (size_t)by * N + j0;
    AST(pp + 0, acc.x); AST(pp + 1, acc.y);
    AST(pp + 2, acc.z); AST(pp + 3, acc.w);
  }
  __threadfence();
  grid.sync();
  __threadfence();

  // ---- phase 2: neuron state update (blocks 0..23) ----
  if (bid < NBLK2) {
    int j = bid * 256 + tid;
    float cur = 0.f;
#pragma unroll 8
    for (int c = 0; c < NCH; ++c) cur += ALD(partial + c * N + j);
    const float decay = expf(-0.1f);
    float v = V[j] * decay + cur + 0.015f * noise[j];
    bool spk = v >= 1.0f;
    float s = spk ? 1.0f : 0.0f;
    out[OFF_SPK + j] = s;
    out[OFF_V + j] = spk ? 0.0f : v;
    out[OFF_MEM + j] = 0.95f * mem[j] + 0.05f * s;
    float pr = hist[2 * j + 1];
    out[OFF_HIST + 2 * j] = pr;      // shifted history slot 0 = old slot 1
    out[OFF_HIST + 2 * j + 1] = s;   // new slot 1 = current spikes
    AST(ws_post + j, s);
  }
  __threadfence();
  grid.sync();
  __threadfence();

  // ---- phase 3: stage pre/post -> LDS; action (block 0); W stream (all) ----
  for (int j = tid; j < N; j += 256) {
    post_b[j] = (ALD(ws_post + j) != 0.0f) ? 1 : 0;
    pre_b[j] = (hist[2 * j + 1] != 0.0f) ? 1 : 0;  // inputs are exactly {0,1}
  }
  __syncthreads();

  if (bid == 0) {  // action reduce, recomputed locally: no ws_act handoff
    float acc[10];
#pragma unroll
    for (int k = 0; k < 10; ++k) acc[k] = 0.f;
    for (int j = tid; j < N; j += 256) {
      if (post_b[j]) {
#pragma unroll
        for (int k = 0; k < 10; ++k) acc[k] += Wout[j * 10 + k];
      }
    }
#pragma unroll
    for (int k = 0; k < 10; ++k) {
      float x = acc[k];
      for (int off = 32; off > 0; off >>= 1) x += __shfl_down(x, off, 64);
      if ((tid & 63) == 0) red[tid >> 6][k] = x;
    }
    __syncthreads();
    if (tid < 10)
      out[OFF_ACT + tid] =
          red[0][tid] + red[1][tid] + red[2][tid] + red[3][tid];
  }

  // STDP + decay + clip over W_rec: 6 rows/block, bit-identical to round 0.
  const float kp = 0.008f * expf(-1.0f / 16.8f);
  const float km = -0.0084f * expf(1.0f / 33.7f);
  const float wd = 0.9999999f;  // f32(1 - 1e-7)
  int t4 = tid * 4;
  for (int rr = 0; rr < RPB; ++rr) {
    int i = bid * RPB + rr;
    float a = kp * (float)pre_b[i];   // coeff on post[j]
    float b = km * (float)post_b[i];  // coeff on pre[j]
    const float* wrow = Wrec + (size_t)i * N;
    float* orow = out + (size_t)OFF_W + (size_t)i * N;  // 8B-aligned
    if (a != 0.f || b != 0.f) {
#pragma unroll
      for (int tile = 0; tile < N; tile += 1024) {
        int j0 = tile + t4;
        v4f w = __builtin_nontemporal_load((const v4f*)(wrow + j0));
        float r[4];
#pragma unroll
        for (int c = 0; c < 4; ++c) {
          float po = (float)post_b[j0 + c];
          float pq = (float)pre_b[j0 + c];
          float dw = (w[c] != 0.f) ? (a * po + b * pq) : 0.f;
          r[c] = fminf(fmaxf((w[c] + dw) * wd, -1.5f), 1.5f);
        }
        v2f lo = {r[0], r[1]}, hi = {r[2], r[3]};
        __builtin_nontemporal_store(lo, (v2f*)(orow + j0));
        __builtin_nontemporal_store(hi, (v2f*)(orow + j0 + 2));
      }
    } else {  // silent row: decay+clip only
#pragma unroll
      for (int tile = 0; tile < N; tile += 1024) {
        int j0 = tile + t4;
        v4f w = __builtin_nontemporal_load((const v4f*)(wrow + j0));
        float r[4];
#pragma unroll
        for (int c = 0; c < 4; ++c)
          r[c] = fminf(fmaxf(w[c] * wd, -1.5f), 1.5f);
        v2f lo = {r[0], r[1]}, hi = {r[2], r[3]};
        __builtin_nontemporal_store(lo, (v2f*)(orow + j0));
        __builtin_nontemporal_store(hi, (v2f*)(orow + j0 + 2));
      }
    }
  }
}

extern "C" void kernel_launch(void* const* d_in, const int* in_sizes, int n_in,
                              void* d_out, int out_size, void* d_ws,
                              size_t ws_size, hipStream_t stream) {
  const float* inp = (const float*)d_in[0];    // input_spk (1,1024)
  const float* V = (const float*)d_in[1];      // V (1,6144)
  const float* hist = (const float*)d_in[2];   // spike_history (1,6144,2)
  const float* mem = (const float*)d_in[3];    // mem (1,6144)
  const float* Wrec = (const float*)d_in[4];   // W_rec (6144,6144)
  const float* Win = (const float*)d_in[5];    // W_in (1024,6144)
  const float* Wout = (const float*)d_in[6];   // W_out (6144,10)
  const float* noise = (const float*)d_in[7];  // noise (1,6144)
  float* out = (float*)d_out;
  float* ws = (float*)d_ws;

  void* args[] = {(void*)&Wrec, (void*)&Win,  (void*)&hist,  (void*)&inp,
                  (void*)&V,    (void*)&mem,  (void*)&noise, (void*)&Wout,
                  (void*)&out,  (void*)&ws};
  hipLaunchCooperativeKernel((const void*)snn_fused, dim3(GRID), dim3(256),
                             args, 0, stream);
}

// Round 3
// 307.223 us; speedup vs baseline: 2.7568x; 2.7568x over previous
//
#include <hip/hip_runtime.h>

#define N 6144
#define IN_SZ 1024
#define CHUNK 64
#define NCH_REC (N / CHUNK)        // 96
#define NCH_IN (IN_SZ / CHUNK)     // 16
#define NCH (NCH_REC + NCH_IN)     // 112
#define NBLK2 24                   // K2 blocks (N/256)

typedef float v4f __attribute__((ext_vector_type(4)));
typedef float v2f __attribute__((ext_vector_type(2)));

// output layout (flat float32, return order)
#define OFF_SPK 0
#define OFF_ACT 6144
#define OFF_V 6154
#define OFF_MEM 12298
#define OFF_W 18442                // % 4 == 2 -> row stores are 8B-aligned
#define OFF_HIST 37767178

// K1: sparse spike-driven matvec partials.
// grid (6, 112): x = 1024-col chunk (256 thr * float4), y = 64-row chunk.
// Active rows compacted in ASCENDING order via wave-0 ballot (bit-identical
// summation order vs the gated-loop version), then unconditional pipelineable
// float4 loads.
__global__ __launch_bounds__(256) void k1_matvec(
    const float* __restrict__ Wrec, const float* __restrict__ Win,
    const float* __restrict__ hist, const float* __restrict__ inp,
    float* __restrict__ partial) {
  int by = blockIdx.y;
  bool isRec = by < NCH_REC;
  int rbase = (isRec ? by : by - NCH_REC) * CHUNK;
  const float* M = isRec ? Wrec : Win;
  __shared__ int list[CHUNK];
  __shared__ int cnt;
  int tid = threadIdx.x;
  if (tid < CHUNK) {  // exactly wave 0
    float s = isRec ? hist[2 * (rbase + tid) + 1] : inp[rbase + tid];
    unsigned long long m = __ballot(s != 0.0f);
    int pos = __popcll(m & ((1ull << tid) - 1ull));
    if (s != 0.0f) list[pos] = tid;
    if (tid == 0) cnt = __popcll(m);
  }
  __syncthreads();
  int n = cnt;
  int j0 = (blockIdx.x * 256 + tid) * 4;
  float4 acc = make_float4(0.f, 0.f, 0.f, 0.f);
  for (int k = 0; k < n; ++k) {  // independent loads: compiler can pipeline
    const float4 w = *(const float4*)(M + (size_t)(rbase + list[k]) * N + j0);
    acc.x += w.x; acc.y += w.y; acc.z += w.z; acc.w += w.w;
  }
  *(float4*)(partial + (size_t)by * N + j0) = acc;
}

// K2: neuron state update + per-block action_rate partials. 24 blocks x 256.
__global__ __launch_bounds__(256) void k2_neuron(
    const float* __restrict__ partial, const float* __restrict__ V,
    const float* __restrict__ mem, const float* __restrict__ noise,
    const float* __restrict__ hist, const float* __restrict__ Wout,
    float* __restrict__ out, float* __restrict__ ws_pre,
    float* __restrict__ ws_post, float* __restrict__ ws_act) {
  int tid = threadIdx.x;
  int j = blockIdx.x * 256 + tid;
  float cur = 0.f;
#pragma unroll 8
  for (int c = 0; c < NCH; ++c) cur += partial[c * N + j];
  const float decay = expf(-0.1f);
  float v = V[j] * decay + cur + 0.015f * noise[j];
  bool spk = v >= 1.0f;
  float s = spk ? 1.0f : 0.0f;
  out[OFF_SPK + j] = s;
  out[OFF_V + j] = spk ? 0.0f : v;
  out[OFF_MEM + j] = 0.95f * mem[j] + 0.05f * s;
  float pr = hist[2 * j + 1];
  out[OFF_HIST + 2 * j] = pr;      // shifted history slot 0 = old slot 1
  out[OFF_HIST + 2 * j + 1] = s;   // new slot 1 = current spikes
  ws_pre[j] = pr;
  ws_post[j] = s;

  // action partial: sum_j s_j * Wout[j][k] over this block's 256 neurons
  float acc[10];
#pragma unroll
  for (int k = 0; k < 10; ++k) acc[k] = 0.f;
  if (spk) {
#pragma unroll
    for (int k = 0; k < 10; ++k) acc[k] = Wout[j * 10 + k];
  }
  __shared__ float red[4][10];
#pragma unroll
  for (int k = 0; k < 10; ++k) {
    float x = acc[k];
    for (int off = 32; off > 0; off >>= 1) x += __shfl_down(x, off, 64);
    if ((tid & 63) == 0) red[tid >> 6][k] = x;
  }
  __syncthreads();
  if (tid < 10)
    ws_act[blockIdx.x * 10 + tid] =
        red[0][tid] + red[1][tid] + red[2][tid] + red[3][tid];
}

// K4: STDP + decay + clip over all of W_rec — the 302 MB stream.
// One block per row (6144 blocks, 24/CU), 6 column-tiles of 1024 floats.
// Plain (cacheable) loads: W_rec (151 MB) stays L3-resident across
// iterations; NT stores for the write-once output.
// Block 0 also finishes the action reduce (was K3).
__global__ __launch_bounds__(256) void k4_update(
    const float* __restrict__ Wrec, const float* __restrict__ ws_pre,
    const float* __restrict__ ws_post, const float* __restrict__ ws_act,
    float* __restrict__ out) {
  int tid = threadIdx.x;
  int i = blockIdx.x;
  if (i == 0 && tid < 10) {  // final action reduce (kernel-boundary coherent)
    float s = 0.f;
#pragma unroll
    for (int b = 0; b < NBLK2; ++b) s += ws_act[b * 10 + tid];
    out[OFF_ACT + tid] = s;
  }
  const float kp = 0.008f * expf(-1.0f / 16.8f);
  const float km = -0.0084f * expf(1.0f / 33.7f);
  const float wd = 0.9999999f;  // f32(1 - 1e-7)
  float a = kp * ws_pre[i];   // coeff on post[j]
  float b = km * ws_post[i];  // coeff on pre[j]
  const float* wrow = Wrec + (size_t)i * N;
  float* orow = out + (size_t)OFF_W + (size_t)i * N;  // 8B-aligned
  int t4 = tid * 4;
  if (a != 0.f || b != 0.f) {  // block-uniform; ~19% of rows
#pragma unroll
    for (int tile = 0; tile < N; tile += 1024) {
      int j0 = tile + t4;
      v4f w = *(const v4f*)(wrow + j0);
      v4f po = *(const v4f*)(ws_post + j0);
      v4f pr = *(const v4f*)(ws_pre + j0);
      float r[4];
#pragma unroll
      for (int c = 0; c < 4; ++c) {
        float dw = (w[c] != 0.f) ? (a * po[c] + b * pr[c]) : 0.f;
        r[c] = fminf(fmaxf((w[c] + dw) * wd, -1.5f), 1.5f);
      }
      v2f lo = {r[0], r[1]}, hi = {r[2], r[3]};
      __builtin_nontemporal_store(lo, (v2f*)(orow + j0));
      __builtin_nontemporal_store(hi, (v2f*)(orow + j0 + 2));
    }
  } else {
#pragma unroll
    for (int tile = 0; tile < N; tile += 1024) {
      int j0 = tile + t4;
      v4f w = *(const v4f*)(wrow + j0);
      float r[4];
#pragma unroll
      for (int c = 0; c < 4; ++c)
        r[c] = fminf(fmaxf(w[c] * wd, -1.5f), 1.5f);
      v2f lo = {r[0], r[1]}, hi = {r[2], r[3]};
      __builtin_nontemporal_store(lo, (v2f*)(orow + j0));
      __builtin_nontemporal_store(hi, (v2f*)(orow + j0 + 2));
    }
  }
}

extern "C" void kernel_launch(void* const* d_in, const int* in_sizes, int n_in,
                              void* d_out, int out_size, void* d_ws,
                              size_t ws_size, hipStream_t stream) {
  const float* inp = (const float*)d_in[0];    // input_spk (1,1024)
  const float* V = (const float*)d_in[1];      // V (1,6144)
  const float* hist = (const float*)d_in[2];   // spike_history (1,6144,2)
  const float* mem = (const float*)d_in[3];    // mem (1,6144)
  const float* Wrec = (const float*)d_in[4];   // W_rec (6144,6144)
  const float* Win = (const float*)d_in[5];    // W_in (1024,6144)
  const float* Wout = (const float*)d_in[6];   // W_out (6144,10)
  const float* noise = (const float*)d_in[7];  // noise (1,6144)
  float* out = (float*)d_out;
  float* ws = (float*)d_ws;
  float* partial = ws;                      // 112*6144
  float* ws_pre = ws + (size_t)NCH * N;     // 6144
  float* ws_post = ws_pre + N;              // 6144
  float* ws_act = ws_post + N;              // 240

  k1_matvec<<<dim3(6, NCH), 256, 0, stream>>>(Wrec, Win, hist, inp, partial);
  k2_neuron<<<dim3(NBLK2), 256, 0, stream>>>(partial, V, mem, noise, hist, Wout,
                                             out, ws_pre, ws_post, ws_act);
  k4_update<<<dim3(N), 256, 0, stream>>>(Wrec, ws_pre, ws_post, ws_act, out);
}